// Round 1
// baseline (1755.531 us; speedup 1.0000x reference)
//
#include <hip/hip_runtime.h>

// Tree-RNN forward:
//   h0 = relu(leaf[8192,4096] @ W_emb^T[4096,512] + b_emb)
//   13x: h = relu(h_view[m,1024] @ W_comb^T[1024,512] + b_comb)   (m: 4096..1)
//   out[2] = h_root[1,512] @ W_proj^T + b_proj
// All fp32. NT-GEMM (A rows and W rows both contiguous over K).

#define BM 128
#define BN 64
#define BK 16

template <bool RELU>
__global__ __launch_bounds__(256) void gemm_nt_bias(
    const float* __restrict__ A,    // [M,K] row-major
    const float* __restrict__ B,    // [N,K] row-major (weights)
    const float* __restrict__ bias, // [N]
    float* __restrict__ C,          // [M,N] row-major
    int M, int N, int K)
{
    // K-major LDS tiles, padded +4 floats: write-transpose conflicts <= 2-way (free),
    // float4 reads stay 16B-aligned (132 and 68 are multiples of 4).
    __shared__ __align__(16) float As[BK][BM + 4];
    __shared__ __align__(16) float Bs[BK][BN + 4];

    const int tid  = threadIdx.x;
    const int tx   = tid & 15;         // n micro-tile index (4 cols each)
    const int ty   = tid >> 4;         // m micro-tile index (8 rows each)
    const int arow = tid >> 2;         // 0..63 staging row
    const int kq   = (tid & 3) << 2;   // 0,4,8,12 staging k-quad

    const int mb = blockIdx.x * BM;
    const int nb = blockIdx.y * BN;

    const int r0 = mb + arow;
    const int r1 = r0 + 64;
    const long offA0 = (long)r0 * K;
    const long offA1 = (long)r1 * K;
    const float* Brow = B + (long)(nb + arow) * K;

    float acc[8][4];
#pragma unroll
    for (int i = 0; i < 8; ++i)
#pragma unroll
        for (int j = 0; j < 4; ++j) acc[i][j] = 0.f;

    for (int k0 = 0; k0 < K; k0 += BK) {
        float4 a0 = make_float4(0.f, 0.f, 0.f, 0.f);
        float4 a1 = make_float4(0.f, 0.f, 0.f, 0.f);
        if (r0 < M) a0 = *(const float4*)(A + offA0 + k0 + kq);
        if (r1 < M) a1 = *(const float4*)(A + offA1 + k0 + kq);
        const float4 bv = *(const float4*)(Brow + k0 + kq);

        __syncthreads();  // previous iteration's LDS reads must finish
#pragma unroll
        for (int j = 0; j < 4; ++j) {
            As[kq + j][arow]      = (&a0.x)[j];
            As[kq + j][arow + 64] = (&a1.x)[j];
            Bs[kq + j][arow]      = (&bv.x)[j];
        }
        __syncthreads();

#pragma unroll
        for (int k = 0; k < BK; ++k) {
            const float4 av0 = *(const float4*)&As[k][ty * 8];
            const float4 av1 = *(const float4*)&As[k][ty * 8 + 4];
            const float4 bw  = *(const float4*)&Bs[k][tx * 4];
            const float am[8] = {av0.x, av0.y, av0.z, av0.w, av1.x, av1.y, av1.z, av1.w};
            const float bm[4] = {bw.x, bw.y, bw.z, bw.w};
#pragma unroll
            for (int i = 0; i < 8; ++i)
#pragma unroll
                for (int j = 0; j < 4; ++j)
                    acc[i][j] = fmaf(am[i], bm[j], acc[i][j]);
        }
    }

    const float4 bb = *(const float4*)(bias + nb + tx * 4);
#pragma unroll
    for (int i = 0; i < 8; ++i) {
        const int row = mb + ty * 8 + i;
        if (row < M) {
            float4 o;
            o.x = acc[i][0] + bb.x;
            o.y = acc[i][1] + bb.y;
            o.z = acc[i][2] + bb.z;
            o.w = acc[i][3] + bb.w;
            if (RELU) {
                o.x = fmaxf(o.x, 0.f);
                o.y = fmaxf(o.y, 0.f);
                o.z = fmaxf(o.z, 0.f);
                o.w = fmaxf(o.w, 0.f);
            }
            *(float4*)(C + (long)row * N + nb + tx * 4) = o;
        }
    }
}

// out[c] = dot(h[0,:512], W[c,:]) + b[c], c = 0,1. Two waves, one per class.
__global__ __launch_bounds__(128) void proj_kernel(
    const float* __restrict__ h, const float* __restrict__ W,
    const float* __restrict__ b, float* __restrict__ out)
{
    const int c    = threadIdx.x >> 6;
    const int lane = threadIdx.x & 63;
    float s = 0.f;
#pragma unroll
    for (int j = 0; j < 8; ++j) {
        const int idx = lane + 64 * j;
        s = fmaf(h[idx], W[c * 512 + idx], s);
    }
#pragma unroll
    for (int off = 32; off > 0; off >>= 1) s += __shfl_down(s, off);
    if (lane == 0) out[c] = s + b[c];
}

extern "C" void kernel_launch(void* const* d_in, const int* in_sizes, int n_in,
                              void* d_out, int out_size, void* d_ws, size_t ws_size,
                              hipStream_t stream)
{
    const float* leaf   = (const float*)d_in[0];  // [8192,4096]
    const float* W_emb  = (const float*)d_in[1];  // [512,4096]
    const float* b_emb  = (const float*)d_in[2];  // [512]
    const float* W_comb = (const float*)d_in[3];  // [512,1024]
    const float* b_comb = (const float*)d_in[4];  // [512]
    const float* W_proj = (const float*)d_in[5];  // [2,512]
    const float* b_proj = (const float*)d_in[6];  // [2]
    float* out = (float*)d_out;

    float* buf0 = (float*)d_ws;                 // up to 8192*512 fp32 = 16 MB
    float* buf1 = buf0 + (size_t)8192 * 512;    // up to 4096*512 fp32 = 8 MB

    // Embedding GEMM: [8192,4096] x [512,4096]^T -> [8192,512], relu
    gemm_nt_bias<true><<<dim3(8192 / BM, 512 / BN), 256, 0, stream>>>(
        leaf, W_emb, b_emb, buf0, 8192, 512, 4096);

    // 13 combine levels; input level viewed as [m, 1024] (siblings row-adjacent)
    float* cur = buf0;
    float* nxt = buf1;
    for (int m = 4096; m >= 1; m >>= 1) {
        gemm_nt_bias<true><<<dim3((m + BM - 1) / BM, 512 / BN), 256, 0, stream>>>(
            cur, W_comb, b_comb, nxt, m, 512, 1024);
        float* t = cur; cur = nxt; nxt = t;
    }

    // Root projection -> out[2]
    proj_kernel<<<1, 128, 0, stream>>>(cur, W_proj, b_proj, out);
}

// Round 3
// 776.638 us; speedup vs baseline: 2.2604x; 2.2604x over previous
//
#include <hip/hip_runtime.h>
#include <stdint.h>

// Tree-RNN forward, split-bf16 MFMA version.
//   h0 = relu(leaf[8192,4096] @ W_emb^T + b_emb)
//   13x: h = relu(h[m,1024] @ W_comb^T + b_comb)   (m: 4096..1, siblings row-adjacent)
//   out[2] = h_root @ W_proj^T + b_proj
// fp32 emulated via 3-product bf16 split: A*B ~= Ahi*Bhi + Alo*Bhi + Ahi*Blo
// (residual ~2^-18 rel). Accumulation in fp32 MFMA accs. Intermediates stored
// as bf16 hi/lo planes, written directly by the GEMM epilogue.

typedef float f32x4 __attribute__((ext_vector_type(4)));
typedef short s16x8 __attribute__((ext_vector_type(8)));
typedef unsigned short u16;

__device__ __forceinline__ u16 f2bf(float f) {
    union { float f; uint32_t u; } v; v.f = f;
    return (u16)((v.u + 0x7FFFu + ((v.u >> 16) & 1u)) >> 16);  // RNE
}
__device__ __forceinline__ float bf2f(u16 h) {
    union { uint32_t u; float f; } v; v.u = ((uint32_t)h) << 16;
    return v.f;
}

// fp32 -> (hi, lo) bf16 planes, vectorized by 4
__global__ __launch_bounds__(256) void split_kernel(
    const float* __restrict__ x, u16* __restrict__ hi, u16* __restrict__ lo, int n4)
{
    int i = blockIdx.x * 256 + threadIdx.x;
    if (i >= n4) return;
    float4 v = ((const float4*)x)[i];
    ushort4 h, l;
    h.x = f2bf(v.x); l.x = f2bf(v.x - bf2f(h.x));
    h.y = f2bf(v.y); l.y = f2bf(v.y - bf2f(h.y));
    h.z = f2bf(v.z); l.z = f2bf(v.z - bf2f(h.z));
    h.w = f2bf(v.w); l.w = f2bf(v.w - bf2f(h.w));
    ((ushort4*)hi)[i] = h;
    ((ushort4*)lo)[i] = l;
}

// Split-bf16 NT GEMM: C[M,512] = relu(A[M,K] @ B[512,K]^T + bias), C as hi/lo planes.
// T x T tile, 4 waves (2x2), each wave T/2 x T/2 via (T/32)^2 frags of 16x16x32.
// A source: fp32 (AFP32, split on the fly) or bf16 hi/lo planes.
// LDS rows padded to 40 u16 = 80 B -> 2-way bank conflicts (free).
template <int T, bool AFP32>
__global__ __launch_bounds__(256, 2) void gemm_split(
    const float* __restrict__ Af,
    const u16* __restrict__ Ahi_g, const u16* __restrict__ Alo_g,
    const u16* __restrict__ Bhi_g, const u16* __restrict__ Blo_g,
    const float* __restrict__ bias,
    u16* __restrict__ Chi, u16* __restrict__ Clo,
    int K)
{
    constexpr int N = 512;
    constexpr int FM = T / 32;   // frags per wave dim: 4 (T=128) or 2 (T=64)
    constexpr int LDW = 40;
    __shared__ u16 Ah[T][LDW], Al[T][LDW], Bh[T][LDW], Bl[T][LDW];

    const int tid  = threadIdx.x;
    const int wid  = tid >> 6;
    const int lane = tid & 63;
    const int mb = blockIdx.x * T;
    const int nb = blockIdx.y * T;
    const int wm = (wid >> 1) * (T / 2);
    const int wn = (wid & 1) * (T / 2);

    // staging assignment: (row, 16-elem k-half) slots
    bool doA, doB; int srow, skh;
    if constexpr (T == 128) {
        doA = true; doB = true; srow = tid >> 1; skh = (tid & 1) * 16;
    } else {
        doA = (tid < 128); doB = !doA;
        const int t2 = tid & 127; srow = t2 >> 1; skh = (t2 & 1) * 16;
    }
    const long a_off = (long)(mb + srow) * K + skh;
    const long b_off = (long)(nb + srow) * K + skh;

    f32x4 acc[FM][FM];
    const f32x4 zero = {0.f, 0.f, 0.f, 0.f};
#pragma unroll
    for (int i = 0; i < FM; ++i)
#pragma unroll
        for (int j = 0; j < FM; ++j) acc[i][j] = zero;

    s16x8 rah0, rah1, ral0, ral1, rbh0, rbh1, rbl0, rbl1;

    auto load_tile = [&](int k0) {
        if (doA) {
            if constexpr (AFP32) {
                const float* p = Af + a_off + k0;
                float fa[16];
                *(float4*)(fa)      = *(const float4*)(p);
                *(float4*)(fa + 4)  = *(const float4*)(p + 4);
                *(float4*)(fa + 8)  = *(const float4*)(p + 8);
                *(float4*)(fa + 12) = *(const float4*)(p + 12);
#pragma unroll
                for (int j = 0; j < 8; ++j) {
                    u16 h = f2bf(fa[j]);
                    rah0[j] = (short)h; ral0[j] = (short)f2bf(fa[j] - bf2f(h));
                }
#pragma unroll
                for (int j = 0; j < 8; ++j) {
                    u16 h = f2bf(fa[8 + j]);
                    rah1[j] = (short)h; ral1[j] = (short)f2bf(fa[8 + j] - bf2f(h));
                }
            } else {
                rah0 = *(const s16x8*)(Ahi_g + a_off + k0);
                rah1 = *(const s16x8*)(Ahi_g + a_off + k0 + 8);
                ral0 = *(const s16x8*)(Alo_g + a_off + k0);
                ral1 = *(const s16x8*)(Alo_g + a_off + k0 + 8);
            }
        }
        if (doB) {
            rbh0 = *(const s16x8*)(Bhi_g + b_off + k0);
            rbh1 = *(const s16x8*)(Bhi_g + b_off + k0 + 8);
            rbl0 = *(const s16x8*)(Blo_g + b_off + k0);
            rbl1 = *(const s16x8*)(Blo_g + b_off + k0 + 8);
        }
    };

    load_tile(0);

    for (int k0 = 0; k0 < K; k0 += 32) {
        if (doA) {
            *(s16x8*)&Ah[srow][skh]     = rah0;
            *(s16x8*)&Ah[srow][skh + 8] = rah1;
            *(s16x8*)&Al[srow][skh]     = ral0;
            *(s16x8*)&Al[srow][skh + 8] = ral1;
        }
        if (doB) {
            *(s16x8*)&Bh[srow][skh]     = rbh0;
            *(s16x8*)&Bh[srow][skh + 8] = rbh1;
            *(s16x8*)&Bl[srow][skh]     = rbl0;
            *(s16x8*)&Bl[srow][skh + 8] = rbl1;
        }
        __syncthreads();

        if (k0 + 32 < K) load_tile(k0 + 32);  // overlap next-tile HBM with MFMA

        const int r0 = lane & 15;
        const int kc = (lane >> 4) * 8;
        s16x8 afh[FM], afl[FM], bfh[FM], bfl[FM];
#pragma unroll
        for (int i = 0; i < FM; ++i) {
            afh[i] = *(const s16x8*)&Ah[wm + 16 * i + r0][kc];
            afl[i] = *(const s16x8*)&Al[wm + 16 * i + r0][kc];
            bfh[i] = *(const s16x8*)&Bh[wn + 16 * i + r0][kc];
            bfl[i] = *(const s16x8*)&Bl[wn + 16 * i + r0][kc];
        }
#pragma unroll
        for (int i = 0; i < FM; ++i)
#pragma unroll
            for (int j = 0; j < FM; ++j) {
                acc[i][j] = __builtin_amdgcn_mfma_f32_16x16x32_bf16(afh[i], bfh[j], acc[i][j], 0, 0, 0);
                acc[i][j] = __builtin_amdgcn_mfma_f32_16x16x32_bf16(afl[i], bfh[j], acc[i][j], 0, 0, 0);
                acc[i][j] = __builtin_amdgcn_mfma_f32_16x16x32_bf16(afh[i], bfl[j], acc[i][j], 0, 0, 0);
            }
        __syncthreads();
    }

    // epilogue: bias + relu in fp32, split to hi/lo planes
    float bj[FM];
#pragma unroll
    for (int j = 0; j < FM; ++j) bj[j] = bias[nb + wn + 16 * j + (lane & 15)];
#pragma unroll
    for (int i = 0; i < FM; ++i) {
        const int grow_base = mb + wm + 16 * i + ((lane >> 4) << 2);
#pragma unroll
        for (int j = 0; j < FM; ++j) {
            const int gcol = nb + wn + 16 * j + (lane & 15);
#pragma unroll
            for (int r = 0; r < 4; ++r) {
                float v = acc[i][j][r] + bj[j];
                v = fmaxf(v, 0.f);
                u16 h = f2bf(v);
                const long idx = (long)(grow_base + r) * N + gcol;
                Chi[idx] = h;
                Clo[idx] = f2bf(v - bf2f(h));
            }
        }
    }
}

// tiny levels (m <= 32): one output per thread, fp32 dot from hi/lo planes
__global__ __launch_bounds__(256) void tail_kernel(
    const u16* __restrict__ Hhi, const u16* __restrict__ Hlo,  // [m][1024] view
    const float* __restrict__ W,     // [512][1024] fp32
    const float* __restrict__ bias,  // [512]
    u16* __restrict__ Ohi, u16* __restrict__ Olo,              // [m][512]
    int m)
{
    const int gid = blockIdx.x * 256 + threadIdx.x;
    if (gid >= m * 512) return;
    const int row = gid >> 9, n = gid & 511;
    const u16* hh = Hhi + (long)row * 1024;
    const u16* hl = Hlo + (long)row * 1024;
    const float* w = W + (long)n * 1024;
    float s = 0.f;
    for (int k = 0; k < 1024; k += 8) {
        s16x8 vh = *(const s16x8*)(hh + k);
        s16x8 vl = *(const s16x8*)(hl + k);
        float4 w0 = *(const float4*)(w + k);
        float4 w1 = *(const float4*)(w + k + 4);
        const float* wp = &w0.x;
#pragma unroll
        for (int j = 0; j < 4; ++j)
            s = fmaf(bf2f((u16)vh[j]) + bf2f((u16)vl[j]), wp[j], s);
        const float* wq = &w1.x;
#pragma unroll
        for (int j = 0; j < 4; ++j)
            s = fmaf(bf2f((u16)vh[4 + j]) + bf2f((u16)vl[4 + j]), wq[j], s);
    }
    float v = fmaxf(s + bias[n], 0.f);
    u16 h = f2bf(v);
    Ohi[gid] = h;
    Olo[gid] = f2bf(v - bf2f(h));
}

// root projection: out[c] = dot(h_root, W_proj[c]) + b[c]
__global__ __launch_bounds__(128) void proj_kernel(
    const u16* __restrict__ hhi, const u16* __restrict__ hlo,
    const float* __restrict__ W, const float* __restrict__ b, float* __restrict__ out)
{
    const int c    = threadIdx.x >> 6;
    const int lane = threadIdx.x & 63;
    float s = 0.f;
#pragma unroll
    for (int j = 0; j < 8; ++j) {
        const int idx = lane + 64 * j;
        s = fmaf(bf2f(hhi[idx]) + bf2f(hlo[idx]), W[c * 512 + idx], s);
    }
#pragma unroll
    for (int off = 32; off > 0; off >>= 1) s += __shfl_down(s, off);
    if (lane == 0) out[c] = s + b[c];
}

extern "C" void kernel_launch(void* const* d_in, const int* in_sizes, int n_in,
                              void* d_out, int out_size, void* d_ws, size_t ws_size,
                              hipStream_t stream)
{
    const float* leaf   = (const float*)d_in[0];  // [8192,4096]
    const float* W_emb  = (const float*)d_in[1];  // [512,4096]
    const float* b_emb  = (const float*)d_in[2];  // [512]
    const float* W_comb = (const float*)d_in[3];  // [512,1024]
    const float* b_comb = (const float*)d_in[4];  // [512]
    const float* W_proj = (const float*)d_in[5];  // [2,512]
    const float* b_proj = (const float*)d_in[6];  // [2]
    float* out = (float*)d_out;

    u16* p = (u16*)d_ws;                       // ~35.7 MB total
    u16* WembHi  = p; p += (size_t)512 * 4096;
    u16* WembLo  = p; p += (size_t)512 * 4096;
    u16* WcombHi = p; p += (size_t)512 * 1024;
    u16* WcombLo = p; p += (size_t)512 * 1024;
    u16* h0hi = p; p += (size_t)8192 * 512;
    u16* h0lo = p; p += (size_t)8192 * 512;
    u16* h1hi = p; p += (size_t)4096 * 512;
    u16* h1lo = p; p += (size_t)4096 * 512;

    {   // weight splits (recomputed every call; ws is re-poisoned)
        int n4 = 512 * 4096 / 4;
        split_kernel<<<(n4 + 255) / 256, 256, 0, stream>>>(W_emb, WembHi, WembLo, n4);
        n4 = 512 * 1024 / 4;
        split_kernel<<<(n4 + 255) / 256, 256, 0, stream>>>(W_comb, WcombHi, WcombLo, n4);
    }

    // embedding: fp32 A split on the fly
    gemm_split<128, true><<<dim3(8192 / 128, 512 / 128), 256, 0, stream>>>(
        leaf, nullptr, nullptr, WembHi, WembLo, b_emb, h0hi, h0lo, 4096);

    u16 *chi = h0hi, *clo = h0lo, *nhi = h1hi, *nlo = h1lo;
    for (int m = 4096; m >= 1024; m >>= 1) {
        gemm_split<128, false><<<dim3(m / 128, 512 / 128), 256, 0, stream>>>(
            nullptr, chi, clo, WcombHi, WcombLo, b_comb, nhi, nlo, 1024);
        u16* t;
        t = chi; chi = nhi; nhi = t;
        t = clo; clo = nlo; nlo = t;
    }
    for (int m = 512; m >= 64; m >>= 1) {
        gemm_split<64, false><<<dim3(m / 64, 512 / 64), 256, 0, stream>>>(
            nullptr, chi, clo, WcombHi, WcombLo, b_comb, nhi, nlo, 1024);
        u16* t;
        t = chi; chi = nhi; nhi = t;
        t = clo; clo = nlo; nlo = t;
    }
    for (int m = 32; m >= 1; m >>= 1) {
        tail_kernel<<<(m * 512 + 255) / 256, 256, 0, stream>>>(
            chi, clo, W_comb, b_comb, nhi, nlo, m);
        u16* t;
        t = chi; chi = nhi; nhi = t;
        t = clo; clo = nlo; nlo = t;
    }

    proj_kernel<<<1, 128, 0, stream>>>(chi, clo, W_proj, b_proj, out);
}

// Round 5
// 639.262 us; speedup vs baseline: 2.7462x; 1.2149x over previous
//
#include <hip/hip_runtime.h>
#include <stdint.h>

// Tree-RNN forward, split-bf16 MFMA (32x32x16 shape, high-occupancy 64x64 tiles).
//   h0 = relu(leaf[8192,4096] @ W_emb^T + b_emb)
//   13x: h = relu(h[m,1024] @ W_comb^T + b_comb)   (m: 4096..1)
//   out[2] = h_root @ W_proj^T + b_proj
// fp32 via 3-product bf16 split: AB ~= AhBh + AlBh + AhBl (residual ~2^-17 rel).

typedef float  f32x16 __attribute__((ext_vector_type(16)));
typedef short  s16x8  __attribute__((ext_vector_type(8)));
typedef unsigned short u16;

__device__ __forceinline__ u16 f2bf_rne(float f) {
    union { float f; uint32_t u; } v; v.f = f;
    return (u16)((v.u + 0x7FFFu + ((v.u >> 16) & 1u)) >> 16);
}
__device__ __forceinline__ float bf2f(u16 h) {
    union { uint32_t u; float f; } v; v.u = ((uint32_t)h) << 16;
    return v.f;
}

// fp32 -> (hi, lo) bf16 planes (RNE both), vectorized by 4
__global__ __launch_bounds__(256) void split_kernel(
    const float* __restrict__ x, u16* __restrict__ hi, u16* __restrict__ lo, int n4)
{
    int i = blockIdx.x * 256 + threadIdx.x;
    if (i >= n4) return;
    float4 v = ((const float4*)x)[i];
    ushort4 h, l;
    h.x = f2bf_rne(v.x); l.x = f2bf_rne(v.x - bf2f(h.x));
    h.y = f2bf_rne(v.y); l.y = f2bf_rne(v.y - bf2f(h.y));
    h.z = f2bf_rne(v.z); l.z = f2bf_rne(v.z - bf2f(h.z));
    h.w = f2bf_rne(v.w); l.w = f2bf_rne(v.w - bf2f(h.w));
    ((ushort4*)hi)[i] = h;
    ((ushort4*)lo)[i] = l;
}

// Split-bf16 NT GEMM, C = relu(A[M,K] @ B[512,K]^T + bias) -> hi/lo planes.
// 64x64 tile, 4 waves (2x2), one 32x32 output frag per wave via mfma_32x32x16.
// LDS rows padded to 56 u16 = 112 B: 16B-aligned, 28-bank stride -> even spread.
template <bool AFP32>
__global__ __launch_bounds__(256, 2) void gemm32(
    const float* __restrict__ Af,
    const u16* __restrict__ Ahi_g, const u16* __restrict__ Alo_g,
    const u16* __restrict__ Bhi_g, const u16* __restrict__ Blo_g,
    const float* __restrict__ bias,
    u16* __restrict__ Chi, u16* __restrict__ Clo,
    int K)
{
    constexpr int N = 512;
    constexpr int LDW = 56;
    __shared__ __align__(16) u16 Ah[64][LDW], Al[64][LDW], Bh[64][LDW], Bl[64][LDW];

    const int tid  = threadIdx.x;
    const int wid  = tid >> 6;
    const int lane = tid & 63;
    const int mb = blockIdx.x * 64;
    const int nb = blockIdx.y * 64;
    const int wm = (wid >> 1) * 32;
    const int wn = (wid & 1) * 32;

    // staging: threads 0..127 -> A tile, 128..255 -> B tile. 2 threads/row.
    const bool isA = tid < 128;
    const int  t2   = tid & 127;
    const int  srow = t2 >> 1;           // 0..63
    const int  skh  = (t2 & 1) * 16;     // 0 or 16
    const long g_off = isA ? ((long)(mb + srow) * K + skh)
                           : ((long)(nb + srow) * K + skh);

    f32x16 acc = {}, acc2 = {};
    s16x8 rh0, rh1, rl0, rl1;

    auto load_tile = [&](int k0) {
        if (AFP32 && isA) {
            const float* p = Af + g_off + k0;
            float fa[16];
            *(float4*)(fa)      = *(const float4*)(p);
            *(float4*)(fa + 4)  = *(const float4*)(p + 4);
            *(float4*)(fa + 8)  = *(const float4*)(p + 8);
            *(float4*)(fa + 12) = *(const float4*)(p + 12);
#pragma unroll
            for (int j = 0; j < 16; ++j) {
                union { float f; uint32_t u; } v; v.f = fa[j];
                u16 h = (u16)(v.u >> 16);               // trunc hi
                union { uint32_t u; float f; } hf; hf.u = v.u & 0xFFFF0000u;
                u16 l = f2bf_rne(fa[j] - hf.f);         // RNE lo
                if (j < 8) { rh0[j] = (short)h; rl0[j] = (short)l; }
                else       { rh1[j - 8] = (short)h; rl1[j - 8] = (short)l; }
            }
        } else {
            const u16* ph = isA ? Ahi_g : Bhi_g;
            const u16* pl = isA ? Alo_g : Blo_g;
            rh0 = *(const s16x8*)(ph + g_off + k0);
            rh1 = *(const s16x8*)(ph + g_off + k0 + 8);
            rl0 = *(const s16x8*)(pl + g_off + k0);
            rl1 = *(const s16x8*)(pl + g_off + k0 + 8);
        }
    };

    load_tile(0);

    for (int k0 = 0; k0 < K; k0 += 32) {
        {
            u16 (*Ph)[LDW] = isA ? Ah : Bh;
            u16 (*Pl)[LDW] = isA ? Al : Bl;
            *(s16x8*)&Ph[srow][skh]     = rh0;
            *(s16x8*)&Ph[srow][skh + 8] = rh1;
            *(s16x8*)&Pl[srow][skh]     = rl0;
            *(s16x8*)&Pl[srow][skh + 8] = rl1;
        }
        __syncthreads();

        if (k0 + 32 < K) load_tile(k0 + 32);   // overlap next-tile loads with MFMA

        const int fr  = lane & 31;             // row within 32-frag
        const int off = (lane >> 5) * 8;       // k-octet select
        s16x8 ah0 = *(const s16x8*)&Ah[wm + fr][off];
        s16x8 ah1 = *(const s16x8*)&Ah[wm + fr][16 + off];
        s16x8 al0 = *(const s16x8*)&Al[wm + fr][off];
        s16x8 al1 = *(const s16x8*)&Al[wm + fr][16 + off];
        s16x8 bh0 = *(const s16x8*)&Bh[wn + fr][off];
        s16x8 bh1 = *(const s16x8*)&Bh[wn + fr][16 + off];
        s16x8 bl0 = *(const s16x8*)&Bl[wn + fr][off];
        s16x8 bl1 = *(const s16x8*)&Bl[wn + fr][16 + off];

        acc  = __builtin_amdgcn_mfma_f32_32x32x16_bf16(ah0, bh0, acc,  0, 0, 0);
        acc  = __builtin_amdgcn_mfma_f32_32x32x16_bf16(ah1, bh1, acc,  0, 0, 0);
        acc  = __builtin_amdgcn_mfma_f32_32x32x16_bf16(al0, bh0, acc,  0, 0, 0);
        acc2 = __builtin_amdgcn_mfma_f32_32x32x16_bf16(al1, bh1, acc2, 0, 0, 0);
        acc2 = __builtin_amdgcn_mfma_f32_32x32x16_bf16(ah0, bl0, acc2, 0, 0, 0);
        acc2 = __builtin_amdgcn_mfma_f32_32x32x16_bf16(ah1, bl1, acc2, 0, 0, 0);
        __syncthreads();
    }

    // epilogue: bias + relu in fp32, split to hi/lo planes
    const int fc = lane & 31;
    const float bv = bias[nb + wn + fc];
    const long gcol = nb + wn + fc;
#pragma unroll
    for (int reg = 0; reg < 16; ++reg) {
        const int row = (reg & 3) + 8 * (reg >> 2) + 4 * (lane >> 5);
        float v = acc[reg] + acc2[reg] + bv;
        v = fmaxf(v, 0.f);
        u16 h = f2bf_rne(v);
        const long idx = (long)(mb + wm + row) * N + gcol;
        Chi[idx] = h;
        Clo[idx] = f2bf_rne(v - bf2f(h));
    }
}

// tiny levels (m <= 32): grid (m, 2); h-row staged fp32 in LDS, 1 output/thread
__global__ __launch_bounds__(256) void tail_gemv(
    const u16* __restrict__ Hhi, const u16* __restrict__ Hlo,  // [m][1024] view
    const float* __restrict__ W,     // [512][1024] fp32
    const float* __restrict__ bias,  // [512]
    u16* __restrict__ Ohi, u16* __restrict__ Olo)              // [m][512]
{
    __shared__ float hrow[1024];
    const int row = blockIdx.x;
    const int tid = threadIdx.x;
    const int n   = blockIdx.y * 256 + tid;

    ushort4 hv = ((const ushort4*)(Hhi + (long)row * 1024))[tid];
    ushort4 lv = ((const ushort4*)(Hlo + (long)row * 1024))[tid];
    hrow[4 * tid + 0] = bf2f(hv.x) + bf2f(lv.x);
    hrow[4 * tid + 1] = bf2f(hv.y) + bf2f(lv.y);
    hrow[4 * tid + 2] = bf2f(hv.z) + bf2f(lv.z);
    hrow[4 * tid + 3] = bf2f(hv.w) + bf2f(lv.w);
    __syncthreads();

    const float* w = W + (long)n * 1024;
    float s = 0.f;
#pragma unroll 8
    for (int k = 0; k < 1024; k += 4) {
        float4 wv = *(const float4*)(w + k);
        s = fmaf(hrow[k + 0], wv.x, s);
        s = fmaf(hrow[k + 1], wv.y, s);
        s = fmaf(hrow[k + 2], wv.z, s);
        s = fmaf(hrow[k + 3], wv.w, s);
    }
    float v = fmaxf(s + bias[n], 0.f);
    u16 h = f2bf_rne(v);
    Ohi[(long)row * 512 + n] = h;
    Olo[(long)row * 512 + n] = f2bf_rne(v - bf2f(h));
}

// root projection: out[c] = dot(h_root, W_proj[c]) + b[c]
__global__ __launch_bounds__(128) void proj_kernel(
    const u16* __restrict__ hhi, const u16* __restrict__ hlo,
    const float* __restrict__ W, const float* __restrict__ b, float* __restrict__ out)
{
    const int c    = threadIdx.x >> 6;
    const int lane = threadIdx.x & 63;
    float s = 0.f;
#pragma unroll
    for (int j = 0; j < 8; ++j) {
        const int idx = lane + 64 * j;
        s = fmaf(bf2f(hhi[idx]) + bf2f(hlo[idx]), W[c * 512 + idx], s);
    }
#pragma unroll
    for (int off = 32; off > 0; off >>= 1) s += __shfl_down(s, off);
    if (lane == 0) out[c] = s + b[c];
}

extern "C" void kernel_launch(void* const* d_in, const int* in_sizes, int n_in,
                              void* d_out, int out_size, void* d_ws, size_t ws_size,
                              hipStream_t stream)
{
    const float* leaf   = (const float*)d_in[0];  // [8192,4096]
    const float* W_emb  = (const float*)d_in[1];  // [512,4096]
    const float* b_emb  = (const float*)d_in[2];  // [512]
    const float* W_comb = (const float*)d_in[3];  // [512,1024]
    const float* b_comb = (const float*)d_in[4];  // [512]
    const float* W_proj = (const float*)d_in[5];  // [2,512]
    const float* b_proj = (const float*)d_in[6];  // [2]
    float* out = (float*)d_out;

    u16* p = (u16*)d_ws;                       // ~34 MB total
    u16* WembHi  = p; p += (size_t)512 * 4096;
    u16* WembLo  = p; p += (size_t)512 * 4096;
    u16* WcombHi = p; p += (size_t)512 * 1024;
    u16* WcombLo = p; p += (size_t)512 * 1024;
    u16* h0hi = p; p += (size_t)8192 * 512;
    u16* h0lo = p; p += (size_t)8192 * 512;
    u16* h1hi = p; p += (size_t)4096 * 512;
    u16* h1lo = p; p += (size_t)4096 * 512;

    {   // weight splits (recomputed every call; ws is re-poisoned)
        int n4 = 512 * 4096 / 4;
        split_kernel<<<(n4 + 255) / 256, 256, 0, stream>>>(W_emb, WembHi, WembLo, n4);
        n4 = 512 * 1024 / 4;
        split_kernel<<<(n4 + 255) / 256, 256, 0, stream>>>(W_comb, WcombHi, WcombLo, n4);
    }

    // embedding: fp32 A split on the fly. grid (128, 8) = 1024 blocks -> 4/CU.
    gemm32<true><<<dim3(8192 / 64, 512 / 64), 256, 0, stream>>>(
        leaf, nullptr, nullptr, WembHi, WembLo, b_emb, h0hi, h0lo, 4096);

    // combine levels m = 4096 .. 64 on MFMA
    u16 *chi = h0hi, *clo = h0lo, *nhi = h1hi, *nlo = h1lo;
    for (int m = 4096; m >= 64; m >>= 1) {
        gemm32<false><<<dim3(m / 64, 512 / 64), 256, 0, stream>>>(
            nullptr, chi, clo, WcombHi, WcombLo, b_comb, nhi, nlo, 1024);
        u16* t;
        t = chi; chi = nhi; nhi = t;
        t = clo; clo = nlo; nlo = t;
    }

    // tail levels m = 32 .. 1 as GEMV
    for (int m = 32; m >= 1; m >>= 1) {
        tail_gemv<<<dim3(m, 2), 256, 0, stream>>>(
            chi, clo, W_comb, b_comb, nhi, nlo);
        u16* t;
        t = chi; chi = nhi; nhi = t;
        t = clo; clo = nlo; nlo = t;
    }

    proj_kernel<<<1, 128, 0, stream>>>(chi, clo, W_proj, b_proj, out);
}